// Round 4
// baseline (258.826 us; speedup 1.0000x reference)
//
#include <hip/hip_runtime.h>
#include <math.h>

#define NN 10000
#define NE 100000
#define BN_EPS 1e-5f

// ---------------------------------------------------------------------------
// K0: prep. Pre-transpose weights, zero accumulators + degree histogram.
//  wT0[i*320+c]: c<256 -> w0[(i*32+(c&31))*8+(c>>5)]; c<288 -> b0; else root0
//  wT1[i*640+c]: c<512 -> w1[(i*64+(c&63))*8+(c>>6)]; c<576 -> b1; else root1
//  wstT[i*256+o]: o<128 -> s_w[o,i]; else t_w[o-128,i]
// ---------------------------------------------------------------------------
__global__ __launch_bounds__(256) void k_prep(
    const float* __restrict__ w0, const float* __restrict__ b0,
    const float* __restrict__ root0,
    const float* __restrict__ w1, const float* __restrict__ b1,
    const float* __restrict__ root1,
    const float* __restrict__ s_w, const float* __restrict__ t_w,
    float* __restrict__ wT0, float* __restrict__ wT1, float* __restrict__ wstT,
    float* __restrict__ st0, float* __restrict__ st1, float* __restrict__ out,
    int* __restrict__ deg)
{
  int gid = blockIdx.x * 256 + threadIdx.x;
  int gsz = gridDim.x * 256;
  for (int idx = gid; idx < 16 * 320; idx += gsz) {
    int i = idx / 320, c = idx - i * 320;
    float v;
    if (c < 256)      v = w0[(i * 32 + (c & 31)) * 8 + (c >> 5)];
    else if (c < 288) v = b0[i * 32 + (c - 256)];
    else              v = root0[i * 32 + (c - 288)];
    wT0[idx] = v;
  }
  for (int idx = gid; idx < 32 * 640; idx += gsz) {
    int i = idx / 640, c = idx - i * 640;
    float v;
    if (c < 512)      v = w1[(i * 64 + (c & 63)) * 8 + (c >> 6)];
    else if (c < 576) v = b1[i * 64 + (c - 512)];
    else              v = root1[i * 64 + (c - 576)];
    wT1[idx] = v;
  }
  for (int idx = gid; idx < 64 * 256; idx += gsz) {
    int i = idx >> 8, o = idx & 255;
    wstT[idx] = (o < 128) ? s_w[o * 64 + i] : t_w[(o - 128) * 64 + i];
  }
  for (int idx = gid; idx < 64 * 128; idx += gsz) out[idx] = 0.f;
  for (int idx = gid; idx < NN; idx += gsz) deg[idx] = 0;
  if (gid < 64)  st0[gid] = 0.f;
  if (gid < 128) st1[gid] = 0.f;
}

// ---------------------------------------------------------------------------
// S1: per-src degree histogram.
// ---------------------------------------------------------------------------
__global__ __launch_bounds__(256) void k_hist(
    const int* __restrict__ ei, int* __restrict__ deg)
{
  int e = blockIdx.x * 256 + threadIdx.x;
  if (e < NE) atomicAdd(&deg[ei[e]], 1);
}

// ---------------------------------------------------------------------------
// S2: exclusive scan of deg -> row_ptr (and cursor copy). Single block.
// ---------------------------------------------------------------------------
__global__ __launch_bounds__(256) void k_scan(
    const int* __restrict__ deg, int* __restrict__ row_ptr,
    int* __restrict__ cursor)
{
  __shared__ int part[256];
  int t = threadIdx.x;
  int base = t * 40;
  int s = 0;
  for (int j = 0; j < 40; ++j) {
    int idx = base + j;
    if (idx < NN) s += deg[idx];
  }
  part[t] = s;
  __syncthreads();
  if (t == 0) {
    int r = 0;
    for (int i = 0; i < 256; ++i) { int v = part[i]; part[i] = r; r += v; }
    row_ptr[NN] = r;  // == NE
  }
  __syncthreads();
  int r = part[t];
  for (int j = 0; j < 40; ++j) {
    int idx = base + j;
    if (idx < NN) { row_ptr[idx] = r; cursor[idx] = r; r += deg[idx]; }
  }
}

// ---------------------------------------------------------------------------
// S3: scatter edges into src-sorted arrays (dstS, eaS).
// ---------------------------------------------------------------------------
__global__ __launch_bounds__(256) void k_scatter(
    const int* __restrict__ ei, const float* __restrict__ ea,
    int* __restrict__ cursor, int* __restrict__ dstS, float* __restrict__ eaS)
{
  int e = blockIdx.x * 256 + threadIdx.x;
  if (e >= NE) return;
  int src = ei[e];
  int p = atomicAdd(&cursor[src], 1);
  dstS[p] = ei[NE + e];
  const float4* ev = (const float4*)(ea + 8 * (size_t)e);
  float4 a = ev[0], b = ev[1];
  float4* ov = (float4*)(eaS + 8 * (size_t)p);
  ov[0] = a; ov[1] = b;
}

// ---------------------------------------------------------------------------
// K1: layer-0 node kernel, register-column GEMV (thread c owns column c).
// ---------------------------------------------------------------------------
__global__ __launch_bounds__(320) void k_node0(
    const float* __restrict__ x, const float* __restrict__ wT0,
    const float* __restrict__ bias0,
    float* __restrict__ G0, float* __restrict__ h0)
{
  int c = threadIdx.x;
  float wc[16];
#pragma unroll
  for (int i = 0; i < 16; ++i) wc[i] = wT0[i * 320 + c];
  float bi = (c >= 288) ? bias0[c - 288] : 0.f;

  int n0 = blockIdx.x * 20;
  for (int n = n0; n < n0 + 20; n += 2) {
    const float4* xa = (const float4*)(x + n * 16);
    float a0 = 0.f, a1 = 0.f;
#pragma unroll
    for (int q = 0; q < 4; ++q) {
      float4 v0 = xa[q], v1 = xa[q + 4];
      a0 = fmaf(v0.x, wc[4 * q + 0], a0); a1 = fmaf(v1.x, wc[4 * q + 0], a1);
      a0 = fmaf(v0.y, wc[4 * q + 1], a0); a1 = fmaf(v1.y, wc[4 * q + 1], a1);
      a0 = fmaf(v0.z, wc[4 * q + 2], a0); a1 = fmaf(v1.z, wc[4 * q + 2], a1);
      a0 = fmaf(v0.w, wc[4 * q + 3], a0); a1 = fmaf(v1.w, wc[4 * q + 3], a1);
    }
    if (c < 288) {
      G0[n * 288 + c]       = a0;
      G0[(n + 1) * 288 + c] = a1;
    } else {
      h0[n * 32 + (c - 288)]       = a0 + bi;
      h0[(n + 1) * 32 + (c - 288)] = a1 + bi;
    }
  }
}

// ---------------------------------------------------------------------------
// K2: layer-0 edge kernel, CSR-by-src. One wave per src node; G row loaded
// once into 9 VGPRs (per 32-lane half); halves alternate edges of same src.
// ---------------------------------------------------------------------------
__global__ __launch_bounds__(256) void k_edge0s(
    const int* __restrict__ row_ptr, const int* __restrict__ dstS,
    const float* __restrict__ eaS,
    const float* __restrict__ G0, float* __restrict__ h0)
{
  int tid = threadIdx.x;
  int lane = tid & 63;
  int o = lane & 31, ph = lane >> 5;
  int wv = blockIdx.x * 4 + (tid >> 6);
  int nw = gridDim.x * 4;
  for (int n = wv; n < NN; n += nw) {
    const float* gr = G0 + (size_t)n * 288;
    float g[8];
#pragma unroll
    for (int k = 0; k < 8; ++k) g[k] = gr[k * 32 + o];
    float gb = gr[256 + o];
    int p1 = row_ptr[n + 1];
    for (int p = row_ptr[n] + ph; p < p1; p += 2) {
      int dst = dstS[p];
      const float4* ev = (const float4*)(eaS + 8 * (size_t)p);
      float4 e0 = ev[0], e1 = ev[1];
      float m = gb;
      m = fmaf(e0.x, g[0], m); m = fmaf(e0.y, g[1], m);
      m = fmaf(e0.z, g[2], m); m = fmaf(e0.w, g[3], m);
      m = fmaf(e1.x, g[4], m); m = fmaf(e1.y, g[5], m);
      m = fmaf(e1.z, g[6], m); m = fmaf(e1.w, g[7], m);
      unsafeAtomicAdd(&h0[(size_t)dst * 32 + o], m);
    }
  }
}

// ---------------------------------------------------------------------------
// K3/K6: per-column sum & sumsq over N rows (BN stats), atomic partials.
// ---------------------------------------------------------------------------
template <int C>
__global__ __launch_bounds__(256) void k_stats(
    const float* __restrict__ h, float* __restrict__ st)
{
  const int RPB = 256 / C;
  int tid = threadIdx.x;
  int col = tid % C, rg = tid / C;
  float s1 = 0.f, s2 = 0.f;
  int step = gridDim.x * RPB;
  for (int n = blockIdx.x * RPB + rg; n < NN; n += step) {
    float v = h[n * C + col];
    s1 += v; s2 += v * v;
  }
  __shared__ float l1[256], l2[256];
  l1[tid] = s1; l2[tid] = s2;
  __syncthreads();
  if (tid < C) {
    for (int r = 1; r < RPB; ++r) { s1 += l1[r * C + tid]; s2 += l2[r * C + tid]; }
    unsafeAtomicAdd(&st[tid], s1);
    unsafeAtomicAdd(&st[C + tid], s2);
  }
}

// ---------------------------------------------------------------------------
// K4a: x1 = relu(bn0(h0)), IN-PLACE on h0.
// ---------------------------------------------------------------------------
__global__ __launch_bounds__(256) void k_x1(
    float* __restrict__ h0, const float* __restrict__ st0,
    const float* __restrict__ g0, const float* __restrict__ be0)
{
  __shared__ float sc[32], sh[32];
  int tid = threadIdx.x;
  if (tid < 32) {
    float mu  = st0[tid] * (1.0f / NN);
    float var = st0[32 + tid] * (1.0f / NN) - mu * mu;
    float s   = g0[tid] * rsqrtf(var + BN_EPS);
    sc[tid] = s;
    sh[tid] = be0[tid] - mu * s;
  }
  __syncthreads();
  const int NV = NN * 8;
  for (int i = blockIdx.x * 256 + tid; i < NV; i += gridDim.x * 256) {
    float4 v = ((const float4*)h0)[i];
    int c0 = (i * 4) & 31;
    v.x = fmaxf(fmaf(v.x, sc[c0],     sh[c0]),     0.f);
    v.y = fmaxf(fmaf(v.y, sc[c0 + 1], sh[c0 + 1]), 0.f);
    v.z = fmaxf(fmaf(v.z, sc[c0 + 2], sh[c0 + 2]), 0.f);
    v.w = fmaxf(fmaf(v.w, sc[c0 + 3], sh[c0 + 3]), 0.f);
    ((float4*)h0)[i] = v;
  }
}

// ---------------------------------------------------------------------------
// K4b: layer-1 node kernel, register-column GEMV (thread t owns cols 2t,2t+1).
// ---------------------------------------------------------------------------
__global__ __launch_bounds__(320) void k_node1(
    const float* __restrict__ x1, const float* __restrict__ wT1,
    const float* __restrict__ bias1,
    float* __restrict__ G1, float* __restrict__ h1)
{
  int t = threadIdx.x;
  float wa[32], wb[32];
#pragma unroll
  for (int i = 0; i < 32; ++i) {
    float2 w2 = *(const float2*)(wT1 + i * 640 + 2 * t);
    wa[i] = w2.x; wb[i] = w2.y;
  }
  float bia = 0.f, bib = 0.f;
  if (t >= 288) { bia = bias1[2 * (t - 288)]; bib = bias1[2 * (t - 288) + 1]; }

  int n0 = blockIdx.x * 20;
  for (int n = n0; n < n0 + 20; n += 2) {
    const float4* xa = (const float4*)(x1 + n * 32);
    float a00 = 0.f, a01 = 0.f, a10 = 0.f, a11 = 0.f;
#pragma unroll
    for (int q = 0; q < 8; ++q) {
      float4 v0 = xa[q], v1 = xa[q + 8];
      a00 = fmaf(v0.x, wa[4 * q + 0], a00); a01 = fmaf(v0.x, wb[4 * q + 0], a01);
      a00 = fmaf(v0.y, wa[4 * q + 1], a00); a01 = fmaf(v0.y, wb[4 * q + 1], a01);
      a00 = fmaf(v0.z, wa[4 * q + 2], a00); a01 = fmaf(v0.z, wb[4 * q + 2], a01);
      a00 = fmaf(v0.w, wa[4 * q + 3], a00); a01 = fmaf(v0.w, wb[4 * q + 3], a01);
      a10 = fmaf(v1.x, wa[4 * q + 0], a10); a11 = fmaf(v1.x, wb[4 * q + 0], a11);
      a10 = fmaf(v1.y, wa[4 * q + 1], a10); a11 = fmaf(v1.y, wb[4 * q + 1], a11);
      a10 = fmaf(v1.z, wa[4 * q + 2], a10); a11 = fmaf(v1.z, wb[4 * q + 2], a11);
      a10 = fmaf(v1.w, wa[4 * q + 3], a10); a11 = fmaf(v1.w, wb[4 * q + 3], a11);
    }
    if (t < 288) {
      *(float2*)(G1 + n * 576 + 2 * t)       = make_float2(a00, a01);
      *(float2*)(G1 + (n + 1) * 576 + 2 * t) = make_float2(a10, a11);
    } else {
      int o = 2 * (t - 288);
      *(float2*)(h1 + n * 64 + o)       = make_float2(a00 + bia, a01 + bib);
      *(float2*)(h1 + (n + 1) * 64 + o) = make_float2(a10 + bia, a11 + bib);
    }
  }
}

// ---------------------------------------------------------------------------
// K5: layer-1 edge kernel, CSR-by-src. One wave per src node; G row (64 cols
// x 9 k) loaded once into 9 VGPRs/lane, then one atomic row add per edge.
// ---------------------------------------------------------------------------
__global__ __launch_bounds__(256) void k_edge1s(
    const int* __restrict__ row_ptr, const int* __restrict__ dstS,
    const float* __restrict__ eaS,
    const float* __restrict__ G1, float* __restrict__ h1)
{
  int tid = threadIdx.x;
  int o = tid & 63;
  int wv = blockIdx.x * 4 + (tid >> 6);
  int nw = gridDim.x * 4;
  for (int n = wv; n < NN; n += nw) {
    const float* gr = G1 + (size_t)n * 576;
    float g[8];
#pragma unroll
    for (int k = 0; k < 8; ++k) g[k] = gr[k * 64 + o];
    float gb = gr[512 + o];
    int p1 = row_ptr[n + 1];
    for (int p = row_ptr[n]; p < p1; ++p) {
      int dst = dstS[p];
      const float4* ev = (const float4*)(eaS + 8 * (size_t)p);
      float4 e0 = ev[0], e1 = ev[1];
      float m = gb;
      m = fmaf(e0.x, g[0], m); m = fmaf(e0.y, g[1], m);
      m = fmaf(e0.z, g[2], m); m = fmaf(e0.w, g[3], m);
      m = fmaf(e1.x, g[4], m); m = fmaf(e1.y, g[5], m);
      m = fmaf(e1.z, g[6], m); m = fmaf(e1.w, g[7], m);
      unsafeAtomicAdd(&h1[(size_t)dst * 64 + o], m);
    }
  }
}

// ---------------------------------------------------------------------------
// K6b: x2 = relu(bn1(h1)), IN-PLACE on h1.
// ---------------------------------------------------------------------------
__global__ __launch_bounds__(256) void k_x2(
    float* __restrict__ h1, const float* __restrict__ st1,
    const float* __restrict__ g1, const float* __restrict__ be1)
{
  __shared__ float sc[64], sh[64];
  int tid = threadIdx.x;
  if (tid < 64) {
    float mu  = st1[tid] * (1.0f / NN);
    float var = st1[64 + tid] * (1.0f / NN) - mu * mu;
    float s   = g1[tid] * rsqrtf(var + BN_EPS);
    sc[tid] = s;
    sh[tid] = be1[tid] - mu * s;
  }
  __syncthreads();
  const int NV = NN * 16;
  for (int i = blockIdx.x * 256 + tid; i < NV; i += gridDim.x * 256) {
    float4 v = ((const float4*)h1)[i];
    int c0 = (i * 4) & 63;
    v.x = fmaxf(fmaf(v.x, sc[c0],     sh[c0]),     0.f);
    v.y = fmaxf(fmaf(v.y, sc[c0 + 1], sh[c0 + 1]), 0.f);
    v.z = fmaxf(fmaf(v.z, sc[c0 + 2], sh[c0 + 2]), 0.f);
    v.w = fmaxf(fmaf(v.w, sc[c0 + 3], sh[c0 + 3]), 0.f);
    ((float4*)h1)[i] = v;
  }
}

// ---------------------------------------------------------------------------
// K7: head. Thread c (0..127 per 2-wave group) owns output column c in regs.
// Sorted batch -> per-thread accumulator, one atomic per boundary.
// ---------------------------------------------------------------------------
__global__ __launch_bounds__(256) void k_head(
    const float* __restrict__ x2, const float* __restrict__ wstT,
    const float* __restrict__ s_b, const float* __restrict__ t_b,
    const int* __restrict__ batch, float* __restrict__ out)
{
  int tid = threadIdx.x;
  int c = tid & 127, g = tid >> 7;
  int n0 = blockIdx.x * 40 + g * 20;
  int n1 = n0 + 20;
  if (n0 >= NN) return;
  if (n1 > NN) n1 = NN;

  float wsr[64], wtr[64];
#pragma unroll
  for (int k = 0; k < 64; ++k) {
    wsr[k] = wstT[k * 256 + c];
    wtr[k] = wstT[k * 256 + 128 + c];
  }
  float sb = s_b[c], tb = t_b[c];

  int bcur = batch[n0];
  float facc = 0.f;
  for (int n = n0; n < n1; ++n) {
    const float4* xr = (const float4*)(x2 + (size_t)n * 64);
    float as = 0.f, at = 0.f;
#pragma unroll
    for (int q = 0; q < 16; ++q) {
      float4 xv = xr[q];
      as = fmaf(xv.x, wsr[4 * q + 0], as); at = fmaf(xv.x, wtr[4 * q + 0], at);
      as = fmaf(xv.y, wsr[4 * q + 1], as); at = fmaf(xv.y, wtr[4 * q + 1], at);
      as = fmaf(xv.z, wsr[4 * q + 2], as); at = fmaf(xv.z, wtr[4 * q + 2], at);
      as = fmaf(xv.w, wsr[4 * q + 3], as); at = fmaf(xv.w, wtr[4 * q + 3], at);
    }
    float sv = fminf(30.f, fmaxf(-30.f, as + sb));
    float tv = at + tb;
    float f  = tanhf(tv) / (1.f + expf(sv));
    int b = batch[n];
    if (b != bcur) {
      unsafeAtomicAdd(&out[bcur * 128 + c], facc);
      bcur = b; facc = 0.f;
    }
    facc += f;
  }
  unsafeAtomicAdd(&out[bcur * 128 + c], facc);
}

// ---------------------------------------------------------------------------
extern "C" void kernel_launch(void* const* d_in, const int* in_sizes, int n_in,
                              void* d_out, int out_size, void* d_ws, size_t ws_size,
                              hipStream_t stream)
{
  const float* x     = (const float*)d_in[0];
  const int*   ei    = (const int*)d_in[1];
  const float* ea    = (const float*)d_in[2];
  const int*   batch = (const int*)d_in[3];
  // d_in[4] edge_batch: unused by the reference
  const float* w0    = (const float*)d_in[5];
  const float* b0    = (const float*)d_in[6];
  const float* root0 = (const float*)d_in[7];
  const float* bias0 = (const float*)d_in[8];
  const float* g0    = (const float*)d_in[9];
  const float* be0   = (const float*)d_in[10];
  const float* w1    = (const float*)d_in[11];
  const float* b1    = (const float*)d_in[12];
  const float* root1 = (const float*)d_in[13];
  const float* bias1 = (const float*)d_in[14];
  const float* g1    = (const float*)d_in[15];
  const float* be1   = (const float*)d_in[16];
  const float* s_w   = (const float*)d_in[17];
  const float* s_b   = (const float*)d_in[18];
  const float* t_w   = (const float*)d_in[19];
  const float* t_b   = (const float*)d_in[20];
  float* out = (float*)d_out;

  float* ws   = (float*)d_ws;
  float* G0   = ws;  ws += 2880000;   // N*288
  float* G1   = ws;  ws += 5760000;   // N*576
  float* h0   = ws;  ws += 320000;    // N*32   (becomes x1 in-place)
  float* h1   = ws;  ws += 640000;    // N*64   (becomes x2 in-place)
  float* st0  = ws;  ws += 64;
  float* st1  = ws;  ws += 128;
  float* wstT = ws;  ws += 16384;     // 64x256 transposed head weights
  float* wT0  = ws;  ws += 5120;      // 16x320
  float* wT1  = ws;  ws += 20480;     // 32x640
  float* eaS  = ws;  ws += 800000;    // E*8 src-sorted edge attrs
  int*   iw   = (int*)ws;
  int* deg     = iw;  iw += NN;
  int* row_ptr = iw;  iw += NN + 1;
  int* cursor  = iw;  iw += NN;
  int* dstS    = iw;  iw += NE;

  hipLaunchKernelGGL(k_prep, dim3(64), dim3(256), 0, stream,
                     w0, b0, root0, w1, b1, root1, s_w, t_w,
                     wT0, wT1, wstT, st0, st1, out, deg);
  hipLaunchKernelGGL(k_hist, dim3((NE + 255) / 256), dim3(256), 0, stream, ei, deg);
  hipLaunchKernelGGL(k_scan, dim3(1), dim3(256), 0, stream, deg, row_ptr, cursor);
  hipLaunchKernelGGL(k_scatter, dim3((NE + 255) / 256), dim3(256), 0, stream,
                     ei, ea, cursor, dstS, eaS);
  hipLaunchKernelGGL(k_node0, dim3(500), dim3(320), 0, stream,
                     x, wT0, bias0, G0, h0);
  hipLaunchKernelGGL(k_edge0s, dim3(625), dim3(256), 0, stream,
                     row_ptr, dstS, eaS, G0, h0);
  hipLaunchKernelGGL(k_stats<32>, dim3(64), dim3(256), 0, stream, h0, st0);
  hipLaunchKernelGGL(k_x1, dim3(160), dim3(256), 0, stream, h0, st0, g0, be0);
  hipLaunchKernelGGL(k_node1, dim3(500), dim3(320), 0, stream,
                     h0, wT1, bias1, G1, h1);
  hipLaunchKernelGGL(k_edge1s, dim3(625), dim3(256), 0, stream,
                     row_ptr, dstS, eaS, G1, h1);
  hipLaunchKernelGGL(k_stats<64>, dim3(128), dim3(256), 0, stream, h1, st1);
  hipLaunchKernelGGL(k_x2, dim3(320), dim3(256), 0, stream, h1, st1, g1, be1);
  hipLaunchKernelGGL(k_head, dim3(250), dim3(256), 0, stream,
                     h1, wstT, s_b, t_b, batch, out);
}